// Round 2
// baseline (1064.385 us; speedup 1.0000x reference)
//
#include <hip/hip_runtime.h>
#include <hip/hip_bf16.h>
#include <stdint.h>

#define D 128
#define LAYERS 5
#define BN_EPS 1e-5f

// ---------------- edge_index layout detection ----------------
// Harness contract says integer inputs arrive as int32. Defensively detect
// int64-on-device: indices < 2^31 => every odd int32 word would be 0.

__global__ void detect_kernel(const int* __restrict__ ei, int* __restrict__ flag) {
    if (threadIdx.x == 0 && blockIdx.x == 0) {
        int allz = 1;
#pragma unroll
        for (int i = 0; i < 16; ++i) allz &= (ei[2 * i + 1] == 0);
        *flag = allz;  // 1 => int64 layout, 0 => int32 layout
    }
}

// ---------------- CSR build (dst -> incoming edges) ----------------

__global__ __launch_bounds__(256) void hist_kernel(const int* __restrict__ ei,
                                                   const int* __restrict__ flag,
                                                   int* __restrict__ deg, int E, int n) {
    int e = blockIdx.x * blockDim.x + threadIdx.x;
    if (e >= E) return;
    int is64 = *flag;
    int d = is64 ? ei[2 * ((size_t)E + e)] : ei[E + e];
    if ((unsigned)d < (unsigned)n) atomicAdd(&deg[d], 1);
}

__global__ __launch_bounds__(1024) void scan_kernel(const int* __restrict__ deg,
                                                    int* __restrict__ off, int n) {
    __shared__ int tsum[1024];
    int t = threadIdx.x;
    int CH = (n + 1023) >> 10;
    int lo = t * CH;
    int hi = lo + CH; if (hi > n) hi = n;
    int s = 0;
    for (int i = lo; i < hi; ++i) s += deg[i];
    tsum[t] = s;
    __syncthreads();
    for (int d = 1; d < 1024; d <<= 1) {
        int v = (t >= d) ? tsum[t - d] : 0;
        __syncthreads();
        tsum[t] += v;
        __syncthreads();
    }
    int run = tsum[t] - s;  // exclusive prefix
    for (int i = lo; i < hi; ++i) { off[i] = run; run += deg[i]; }
    if (t == 1023) off[n] = tsum[1023];
}

__global__ __launch_bounds__(256) void fill_kernel(const int* __restrict__ ei,
                                                   const int* __restrict__ flag,
                                                   const int* __restrict__ off,
                                                   int* __restrict__ cursor,
                                                   int2* __restrict__ pack, int E, int n) {
    int e = blockIdx.x * blockDim.x + threadIdx.x;
    if (e >= E) return;
    int is64 = *flag;
    int d = is64 ? ei[2 * ((size_t)E + e)] : ei[E + e];
    int s = is64 ? ei[2 * (size_t)e] : ei[e];
    if ((unsigned)d >= (unsigned)n || (unsigned)s >= (unsigned)n) return;
    int p = atomicAdd(&cursor[d], 1);
    pack[off[d] + p] = make_int2(s, e);
}

// ---------------- aggregate: out[i] = h[i] + sum_j relu(h[src]+ea) ----------------
// one wave per node, float2 per lane (64 lanes * 2 = 128 cols)

__global__ __launch_bounds__(256) void agg_kernel(const float* __restrict__ h,
                                                  const float* __restrict__ ea,
                                                  const int* __restrict__ off,
                                                  const int2* __restrict__ pack,
                                                  float* __restrict__ out, int n) {
    int node = blockIdx.x * 4 + (threadIdx.x >> 6);
    if (node >= n) return;
    int lane = threadIdx.x & 63;
    int c = lane * 2;
    float2 acc = *(const float2*)(h + (size_t)node * D + c);
    int e = off[node], end = off[node + 1];
    for (; e + 2 <= end; e += 2) {
        int2 p0 = pack[e];
        int2 p1 = pack[e + 1];
        float2 a0 = *(const float2*)(h  + (size_t)p0.x * D + c);
        float2 b0 = *(const float2*)(ea + (size_t)p0.y * D + c);
        float2 a1 = *(const float2*)(h  + (size_t)p1.x * D + c);
        float2 b1 = *(const float2*)(ea + (size_t)p1.y * D + c);
        acc.x += fmaxf(a0.x + b0.x, 0.f) + fmaxf(a1.x + b1.x, 0.f);
        acc.y += fmaxf(a0.y + b0.y, 0.f) + fmaxf(a1.y + b1.y, 0.f);
    }
    if (e < end) {
        int2 p0 = pack[e];
        float2 a0 = *(const float2*)(h  + (size_t)p0.x * D + c);
        float2 b0 = *(const float2*)(ea + (size_t)p0.y * D + c);
        acc.x += fmaxf(a0.x + b0.x, 0.f);
        acc.y += fmaxf(a0.y + b0.y, 0.f);
    }
    *(float2*)(out + (size_t)node * D + c) = acc;
}

// ---------------- GEMM: out[N,128] = f(A)[N,128] @ W[128,128] + bias ----------------
// MODE 1: f = identity; also accumulate column sum/sumsq into colstats (for BN)
// MODE 2: f(x) = relu(scale[k]*x + shift[k])  (BN+ReLU folded into the load)
// block: 256 threads, 64 rows/block; thread = (cx: 4 cols, ry: 8 rows) -> 32 accs

template <int MODE>
__global__ __launch_bounds__(256) void gemm_kernel(const float* __restrict__ A,
                                                   const float* __restrict__ W,
                                                   const float* __restrict__ bias,
                                                   float* __restrict__ out,
                                                   const float* __restrict__ ss,
                                                   float* __restrict__ colstats, int n) {
    __shared__ float Wb[64][128];
    __shared__ float Hb[64][68];
    const int t = threadIdx.x;
    const int cx = t & 31;   // cols 4*cx .. 4*cx+3
    const int ry = t >> 5;   // rows ry*8 .. ry*8+7
    const int row0 = blockIdx.x * 64;

    float acc[8][4];
    float4 bv = *(const float4*)(bias + 4 * cx);
#pragma unroll
    for (int i = 0; i < 8; ++i) {
        acc[i][0] = bv.x; acc[i][1] = bv.y; acc[i][2] = bv.z; acc[i][3] = bv.w;
    }

    for (int kc = 0; kc < 128; kc += 64) {
        // stage W chunk [64][128]
#pragma unroll
        for (int p = 0; p < 8; ++p) {
            int f = t + 256 * p;
            int wr = f >> 5, wc = (f & 31) * 4;
            *(float4*)&Wb[wr][wc] = *(const float4*)(W + (size_t)(kc + wr) * 128 + wc);
        }
        // stage H chunk [64 rows][64 ks]
#pragma unroll
        for (int p = 0; p < 4; ++p) {
            int f = t + 256 * p;
            int hr = f >> 4, hc = (f & 15) * 4;
            int r = row0 + hr;
            float4 v = make_float4(0.f, 0.f, 0.f, 0.f);
            if (r < n) v = *(const float4*)(A + (size_t)r * 128 + kc + hc);
            if (MODE == 2) {
                float4 sc = *(const float4*)(ss + kc + hc);
                float4 sh = *(const float4*)(ss + 128 + kc + hc);
                v.x = fmaxf(fmaf(sc.x, v.x, sh.x), 0.f);
                v.y = fmaxf(fmaf(sc.y, v.y, sh.y), 0.f);
                v.z = fmaxf(fmaf(sc.z, v.z, sh.z), 0.f);
                v.w = fmaxf(fmaf(sc.w, v.w, sh.w), 0.f);
            }
            *(float4*)&Hb[hr][hc] = v;
        }
        __syncthreads();
#pragma unroll 4
        for (int k = 0; k < 64; k += 2) {
            float4 w0 = *(const float4*)&Wb[k][4 * cx];
            float4 w1 = *(const float4*)&Wb[k + 1][4 * cx];
#pragma unroll
            for (int i = 0; i < 8; ++i) {
                float2 h2 = *(const float2*)&Hb[ry * 8 + i][k];
                acc[i][0] = fmaf(h2.x, w0.x, acc[i][0]);
                acc[i][1] = fmaf(h2.x, w0.y, acc[i][1]);
                acc[i][2] = fmaf(h2.x, w0.z, acc[i][2]);
                acc[i][3] = fmaf(h2.x, w0.w, acc[i][3]);
                acc[i][0] = fmaf(h2.y, w1.x, acc[i][0]);
                acc[i][1] = fmaf(h2.y, w1.y, acc[i][1]);
                acc[i][2] = fmaf(h2.y, w1.z, acc[i][2]);
                acc[i][3] = fmaf(h2.y, w1.w, acc[i][3]);
            }
        }
        __syncthreads();
    }

    // write output
#pragma unroll
    for (int i = 0; i < 8; ++i) {
        int r = row0 + ry * 8 + i;
        if (r < n) {
            float4 v = make_float4(acc[i][0], acc[i][1], acc[i][2], acc[i][3]);
            *(float4*)(out + (size_t)r * 128 + 4 * cx) = v;
        }
    }

    if (MODE == 1) {
        // per-thread partial column sums (masked to valid rows)
        float s[4] = {0, 0, 0, 0}, s2[4] = {0, 0, 0, 0};
#pragma unroll
        for (int i = 0; i < 8; ++i) {
            int r = row0 + ry * 8 + i;
            if (r < n) {
#pragma unroll
                for (int j = 0; j < 4; ++j) {
                    s[j] += acc[i][j];
                    s2[j] += acc[i][j] * acc[i][j];
                }
            }
        }
        float* red = &Wb[0][0];  // reuse LDS: need 2048 floats
        __syncthreads();
#pragma unroll
        for (int j = 0; j < 4; ++j) {
            red[(cx * 4 + j) * 8 + ry] = s[j];
            red[1024 + (cx * 4 + j) * 8 + ry] = s2[j];
        }
        __syncthreads();
        if (t < 128) {
            float ts = 0.f, ts2 = 0.f;
#pragma unroll
            for (int g = 0; g < 8; ++g) {
                ts += red[t * 8 + g];
                ts2 += red[1024 + t * 8 + g];
            }
            atomicAdd(&colstats[t], ts);
            atomicAdd(&colstats[128 + t], ts2);
        }
    }
}

// ---------------- BN finalize: scale/shift from colstats ----------------

__global__ __launch_bounds__(128) void bn_kernel(const float* __restrict__ colstats,
                                                 const float* __restrict__ gamma,
                                                 const float* __restrict__ beta,
                                                 float* __restrict__ ss, float inv_n) {
    int t = threadIdx.x;
    if (t < D) {
        float mu = colstats[t] * inv_n;
        float var = colstats[D + t] * inv_n - mu * mu;
        float inv = rsqrtf(var + BN_EPS);
        float sc = gamma[t] * inv;
        ss[t] = sc;
        ss[D + t] = beta[t] - mu * sc;
    }
}

// ---------------- launch ----------------

extern "C" void kernel_launch(void* const* d_in, const int* in_sizes, int n_in,
                              void* d_out, int out_size, void* d_ws, size_t ws_size,
                              hipStream_t stream) {
    const float* x      = (const float*)d_in[0];
    const int*   ei     = (const int*)d_in[1];   // int32 per harness contract (int64 auto-detected)
    const float* ea     = (const float*)d_in[2];
    const float* W1     = (const float*)d_in[3];
    const float* b1     = (const float*)d_in[4];
    const float* gamma  = (const float*)d_in[5];
    const float* beta   = (const float*)d_in[6];
    const float* W2     = (const float*)d_in[7];
    const float* b2     = (const float*)d_in[8];
    const int N = in_sizes[0] / D;
    const int E = in_sizes[1] / 2;

    char* w = (char*)d_ws;
    auto alloc = [&](size_t bytes) {
        char* p = w;
        w += (bytes + 255) & ~(size_t)255;
        return p;
    };
    int*   off      = (int*)alloc((size_t)(N + 1) * sizeof(int));
    int*   deg      = (int*)alloc((size_t)N * sizeof(int));
    int*   cursor   = (int*)alloc((size_t)N * sizeof(int));
    int*   flag     = (int*)alloc(256);
    float* colstats = (float*)alloc(256 * sizeof(float));
    float* ss       = (float*)alloc(256 * sizeof(float));
    int2*  pack     = (int2*)alloc((size_t)E * sizeof(int2));
    float* A        = (float*)alloc((size_t)N * D * sizeof(float));
    float* OUT      = (float*)d_out;

    // CSR build
    detect_kernel<<<1, 64, 0, stream>>>(ei, flag);
    hipMemsetAsync(deg, 0, (size_t)N * sizeof(int), stream);
    hist_kernel<<<(E + 255) / 256, 256, 0, stream>>>(ei, flag, deg, E, N);
    scan_kernel<<<1, 1024, 0, stream>>>(deg, off, N);
    hipMemsetAsync(cursor, 0, (size_t)N * sizeof(int), stream);
    fill_kernel<<<(E + 255) / 256, 256, 0, stream>>>(ei, flag, off, cursor, pack, E, N);

    // layer buffer schedule with only {OUT, A}:
    //  l even: agg hin->OUT, gemm1 OUT->A, gemm2 A->OUT
    //  l odd : agg hin->A,   gemm1 A->OUT, gemm2 OUT->A
    // hin: x, OUT, A, OUT, A  -> final output lands in OUT (l=4 even).
    const float* hin = x;
    int gemmBlocks = (N + 63) / 64;
    int aggBlocks  = (N + 3) / 4;
    float inv_n = 1.0f / (float)N;

    for (int l = 0; l < LAYERS; ++l) {
        float* Q = (l % 2 == 0) ? OUT : A;
        float* T = (l % 2 == 0) ? A : OUT;
        agg_kernel<<<aggBlocks, 256, 0, stream>>>(hin, ea, off, pack, Q, N);
        hipMemsetAsync(colstats, 0, 256 * sizeof(float), stream);
        gemm_kernel<1><<<gemmBlocks, 256, 0, stream>>>(Q, W1 + (size_t)l * D * D, b1 + l * D,
                                                       T, nullptr, colstats, N);
        bn_kernel<<<1, 128, 0, stream>>>(colstats, gamma + l * D, beta + l * D, ss, inv_n);
        gemm_kernel<2><<<gemmBlocks, 256, 0, stream>>>(T, W2 + (size_t)l * D * D, b2 + l * D,
                                                       Q, ss, nullptr, N);
        hin = Q;
    }
}

// Round 3
// 931.515 us; speedup vs baseline: 1.1426x; 1.1426x over previous
//
#include <hip/hip_runtime.h>
#include <hip/hip_bf16.h>
#include <stdint.h>

#define D 128
#define LAYERS 5
#define BN_EPS 1e-5f

typedef unsigned int uint32;
typedef __bf16 bf16x8 __attribute__((ext_vector_type(8)));
typedef float f32x4 __attribute__((ext_vector_type(4)));

// fp32 -> bf16 bits, round-to-nearest-even
__device__ inline unsigned short f2bf(float f) {
    uint32 u = __float_as_uint(f);
    return (unsigned short)((u + 0x7fffu + ((u >> 16) & 1u)) >> 16);
}
__device__ inline float bflo(uint32 p) { return __uint_as_float(p << 16); }
__device__ inline float bfhi(uint32 p) { return __uint_as_float(p & 0xffff0000u); }

// ---------------- edge_index layout detection ----------------

__global__ void detect_kernel(const int* __restrict__ ei, int* __restrict__ flag) {
    if (threadIdx.x == 0 && blockIdx.x == 0) {
        int allz = 1;
#pragma unroll
        for (int i = 0; i < 16; ++i) allz &= (ei[2 * i + 1] == 0);
        *flag = allz;  // 1 => int64 layout, 0 => int32 layout
    }
}

// ---------------- CSR build (dst -> incoming edges) ----------------

__global__ __launch_bounds__(256) void hist_kernel(const int* __restrict__ ei,
                                                   const int* __restrict__ flag,
                                                   int* __restrict__ deg, int E, int n) {
    int e = blockIdx.x * blockDim.x + threadIdx.x;
    if (e >= E) return;
    int is64 = *flag;
    int d = is64 ? ei[2 * ((size_t)E + e)] : ei[E + e];
    if ((unsigned)d < (unsigned)n) atomicAdd(&deg[d], 1);
}

__global__ __launch_bounds__(1024) void scan_kernel(const int* __restrict__ deg,
                                                    int* __restrict__ off, int n) {
    __shared__ int tsum[1024];
    int t = threadIdx.x;
    int CH = (n + 1023) >> 10;
    int lo = t * CH;
    int hi = lo + CH; if (hi > n) hi = n;
    int s = 0;
    for (int i = lo; i < hi; ++i) s += deg[i];
    tsum[t] = s;
    __syncthreads();
    for (int d = 1; d < 1024; d <<= 1) {
        int v = (t >= d) ? tsum[t - d] : 0;
        __syncthreads();
        tsum[t] += v;
        __syncthreads();
    }
    int run = tsum[t] - s;  // exclusive prefix
    for (int i = lo; i < hi; ++i) { off[i] = run; run += deg[i]; }
    if (t == 1023) off[n] = tsum[1023];
}

__global__ __launch_bounds__(256) void fill_kernel(const int* __restrict__ ei,
                                                   const int* __restrict__ flag,
                                                   const int* __restrict__ off,
                                                   int* __restrict__ cursor,
                                                   int2* __restrict__ pack, int E, int n) {
    int e = blockIdx.x * blockDim.x + threadIdx.x;
    if (e >= E) return;
    int is64 = *flag;
    int d = is64 ? ei[2 * ((size_t)E + e)] : ei[E + e];
    int s = is64 ? ei[2 * (size_t)e] : ei[e];
    if ((unsigned)d >= (unsigned)n || (unsigned)s >= (unsigned)n) return;
    int p = atomicAdd(&cursor[d], 1);
    pack[off[d] + p] = make_int2(s, e);
}

// ---------------- layer-0 aggregate fused with ea -> bf16 (CSR-ordered) convert ----
// out[i] = x[i] + sum_j relu(x[src]+ea);  eab[p] = bf16(ea[pack[p].y])
// one wave per node, 2 cols per lane

__global__ __launch_bounds__(256) void agg_cvt_kernel(const float* __restrict__ x,
                                                      const float* __restrict__ ea,
                                                      const int* __restrict__ off,
                                                      const int2* __restrict__ pack,
                                                      uint32* __restrict__ eab,
                                                      float* __restrict__ out,
                                                      float* __restrict__ colstats, int n) {
    if (blockIdx.x == 0 && threadIdx.x < 256) colstats[threadIdx.x] = 0.f;
    int node = blockIdx.x * 4 + (threadIdx.x >> 6);
    if (node >= n) return;
    int lane = threadIdx.x & 63;
    int c = lane * 2;
    float2 acc = *(const float2*)(x + (size_t)node * D + c);
    int e = off[node], end = off[node + 1];
    for (; e < end; ++e) {
        int2 p = pack[e];
        float2 ev = *(const float2*)(ea + (size_t)p.y * D + c);
        float2 hs = *(const float2*)(x + (size_t)p.x * D + c);
        acc.x += fmaxf(hs.x + ev.x, 0.f);
        acc.y += fmaxf(hs.y + ev.y, 0.f);
        eab[(size_t)e * 64 + lane] = (uint32)f2bf(ev.x) | ((uint32)f2bf(ev.y) << 16);
    }
    *(float2*)(out + (size_t)node * D + c) = acc;
}

// ---------------- aggregate (layers 1+): bf16 ea, CSR-sequential ----------------

__global__ __launch_bounds__(256) void agg_kernel(const float* __restrict__ h,
                                                  const uint32* __restrict__ eab,
                                                  const int* __restrict__ off,
                                                  const int2* __restrict__ pack,
                                                  float* __restrict__ out,
                                                  float* __restrict__ colstats, int n) {
    if (blockIdx.x == 0 && threadIdx.x < 256) colstats[threadIdx.x] = 0.f;
    int node = blockIdx.x * 4 + (threadIdx.x >> 6);
    if (node >= n) return;
    int lane = threadIdx.x & 63;
    int c = lane * 2;
    float2 acc = *(const float2*)(h + (size_t)node * D + c);
    int e = off[node], end = off[node + 1];
    for (; e + 2 <= end; e += 2) {
        int s0 = pack[e].x, s1 = pack[e + 1].x;
        uint32 e0 = eab[(size_t)e * 64 + lane];
        uint32 e1 = eab[(size_t)(e + 1) * 64 + lane];
        float2 h0 = *(const float2*)(h + (size_t)s0 * D + c);
        float2 h1 = *(const float2*)(h + (size_t)s1 * D + c);
        acc.x += fmaxf(h0.x + bflo(e0), 0.f) + fmaxf(h1.x + bflo(e1), 0.f);
        acc.y += fmaxf(h0.y + bfhi(e0), 0.f) + fmaxf(h1.y + bfhi(e1), 0.f);
    }
    if (e < end) {
        int s0 = pack[e].x;
        uint32 e0 = eab[(size_t)e * 64 + lane];
        float2 h0 = *(const float2*)(h + (size_t)s0 * D + c);
        acc.x += fmaxf(h0.x + bflo(e0), 0.f);
        acc.y += fmaxf(h0.y + bfhi(e0), 0.f);
    }
    *(float2*)(out + (size_t)node * D + c) = acc;
}

// ---------------- W -> Wt bf16 transpose-convert: wt[l][n][k] = bf16(W[l][k][n]) ----

__global__ __launch_bounds__(256) void wt_kernel(const float* __restrict__ W1,
                                                 const float* __restrict__ W2,
                                                 unsigned short* __restrict__ wt) {
    int id = blockIdx.x * 256 + threadIdx.x;
    if (id >= 10 * 16384) return;
    int l = id >> 14;
    int rem = id & 16383;
    int nn = rem >> 7, kk = rem & 127;
    const float* base = (l < 5) ? (W1 + (size_t)l * 16384) : (W2 + (size_t)(l - 5) * 16384);
    wt[(size_t)l * 16384 + nn * 128 + kk] = f2bf(base[kk * 128 + nn]);
}

// ---------------- MFMA GEMM: out[N,128] = f(A)[N,128] @ W[128,128] + bias ----------
// MODE 1: f = id; accumulate column sum/sumsq of OUTPUT into colstats (for BN)
// MODE 2: f(x) = relu(scale[k]*x + shift[k])   (BN+ReLU folded into A-load)
// 256 thr = 4 waves; wave w -> rows blockIdx*64 + w*16; loop 8 col-tiles of 16.
// mfma_f32_16x16x32_bf16 layouts (m89/m91-verified):
//   A: row=l&15, k=8*(l>>4)+j ; B: col=l&15, same k ; D: row=(l>>4)*4+r, col=l&15

template <int MODE>
__global__ __launch_bounds__(256) void gemm_kernel(const float* __restrict__ A,
                                                   const unsigned short* __restrict__ Wt,
                                                   const float* __restrict__ bias,
                                                   float* __restrict__ out,
                                                   const float* __restrict__ ss,
                                                   float* __restrict__ colstats, int n) {
    __shared__ float cs[256];
    const int t = threadIdx.x;
    const int wv = t >> 6, l = t & 63;
    const int lrow = l & 15, lk = l >> 4;
    const int r0 = blockIdx.x * 64 + wv * 16;
    if (MODE == 1) cs[t] = 0.f;
    __syncthreads();

    // A fragments for the wave's 16 rows, all K=128 (4 chunks of 32)
    bf16x8 af[4];
    const int arow = r0 + lrow;
    const bool rowok = arow < n;
    const float* ap = A + (size_t)arow * D + lk * 8;
#pragma unroll
    for (int c = 0; c < 4; ++c) {
        float4 v0 = make_float4(0.f, 0.f, 0.f, 0.f), v1 = v0;
        if (rowok) {
            v0 = *(const float4*)(ap + c * 32);
            v1 = *(const float4*)(ap + c * 32 + 4);
        }
        if (MODE == 2) {
            int kb = c * 32 + lk * 8;
            float4 sc0 = *(const float4*)(ss + kb);
            float4 sc1 = *(const float4*)(ss + kb + 4);
            float4 sh0 = *(const float4*)(ss + D + kb);
            float4 sh1 = *(const float4*)(ss + D + kb + 4);
            v0.x = fmaxf(fmaf(sc0.x, v0.x, sh0.x), 0.f);
            v0.y = fmaxf(fmaf(sc0.y, v0.y, sh0.y), 0.f);
            v0.z = fmaxf(fmaf(sc0.z, v0.z, sh0.z), 0.f);
            v0.w = fmaxf(fmaf(sc0.w, v0.w, sh0.w), 0.f);
            v1.x = fmaxf(fmaf(sc1.x, v1.x, sh1.x), 0.f);
            v1.y = fmaxf(fmaf(sc1.y, v1.y, sh1.y), 0.f);
            v1.z = fmaxf(fmaf(sc1.z, v1.z, sh1.z), 0.f);
            v1.w = fmaxf(fmaf(sc1.w, v1.w, sh1.w), 0.f);
        }
        bf16x8 a;
        a[0] = (__bf16)v0.x; a[1] = (__bf16)v0.y; a[2] = (__bf16)v0.z; a[3] = (__bf16)v0.w;
        a[4] = (__bf16)v1.x; a[5] = (__bf16)v1.y; a[6] = (__bf16)v1.z; a[7] = (__bf16)v1.w;
        af[c] = a;
    }

    const uint4* wt4 = (const uint4*)Wt;  // row n: 128 bf16 = 16 uint4
#pragma unroll
    for (int n0 = 0; n0 < 8; ++n0) {
        const int wcol = n0 * 16 + lrow;
        f32x4 acc = {0.f, 0.f, 0.f, 0.f};
#pragma unroll
        for (int c = 0; c < 4; ++c) {
            union { uint4 u; bf16x8 v; } bu;
            bu.u = wt4[wcol * 16 + c * 4 + lk];
            acc = __builtin_amdgcn_mfma_f32_16x16x32_bf16(af[c], bu.v, acc, 0, 0, 0);
        }
        const float bcol = bias[wcol];
        float s = 0.f, s2 = 0.f;
#pragma unroll
        for (int r = 0; r < 4; ++r) {
            int row = r0 + lk * 4 + r;
            float v = acc[r] + bcol;
            if (row < n) {
                out[(size_t)row * D + wcol] = v;
                if (MODE == 1) { s += v; s2 += v * v; }
            }
        }
        if (MODE == 1) {
            s  += __shfl_xor(s, 16);  s  += __shfl_xor(s, 32);
            s2 += __shfl_xor(s2, 16); s2 += __shfl_xor(s2, 32);
            if (lk == 0) {
                atomicAdd(&cs[wcol], s);
                atomicAdd(&cs[D + wcol], s2);
            }
        }
    }
    if (MODE == 1) {
        __syncthreads();
        if (t < 128) {
            atomicAdd(&colstats[t], cs[t]);
            atomicAdd(&colstats[D + t], cs[D + t]);
        }
    }
}

// ---------------- BN finalize: scale/shift from colstats ----------------

__global__ __launch_bounds__(128) void bn_kernel(const float* __restrict__ colstats,
                                                 const float* __restrict__ gamma,
                                                 const float* __restrict__ beta,
                                                 float* __restrict__ ss, float inv_n) {
    int t = threadIdx.x;
    if (t < D) {
        float mu = colstats[t] * inv_n;
        float var = colstats[D + t] * inv_n - mu * mu;
        float inv = rsqrtf(var + BN_EPS);
        float sc = gamma[t] * inv;
        ss[t] = sc;
        ss[D + t] = beta[t] - mu * sc;
    }
}

// ---------------- launch ----------------

extern "C" void kernel_launch(void* const* d_in, const int* in_sizes, int n_in,
                              void* d_out, int out_size, void* d_ws, size_t ws_size,
                              hipStream_t stream) {
    const float* x      = (const float*)d_in[0];
    const int*   ei     = (const int*)d_in[1];
    const float* ea     = (const float*)d_in[2];
    const float* W1     = (const float*)d_in[3];
    const float* b1     = (const float*)d_in[4];
    const float* gamma  = (const float*)d_in[5];
    const float* beta   = (const float*)d_in[6];
    const float* W2     = (const float*)d_in[7];
    const float* b2     = (const float*)d_in[8];
    const int N = in_sizes[0] / D;
    const int E = in_sizes[1] / 2;

    char* w = (char*)d_ws;
    auto alloc = [&](size_t bytes) {
        char* p = w;
        w += (bytes + 255) & ~(size_t)255;
        return p;
    };
    int*    off      = (int*)alloc((size_t)(N + 1) * sizeof(int));
    int*    deg      = (int*)alloc((size_t)N * sizeof(int));
    int*    cursor   = (int*)alloc((size_t)N * sizeof(int));
    int*    flag     = (int*)alloc(256);
    float*  colstats = (float*)alloc(256 * sizeof(float));
    float*  ss       = (float*)alloc(256 * sizeof(float));
    unsigned short* wt = (unsigned short*)alloc(10 * 16384 * sizeof(unsigned short));
    int2*   pack     = (int2*)alloc((size_t)E * sizeof(int2));
    uint32* eab      = (uint32*)alloc((size_t)E * 64 * sizeof(uint32));
    float*  A        = (float*)alloc((size_t)N * D * sizeof(float));
    float*  OUT      = (float*)d_out;

    // W transpose+bf16 convert, CSR build
    wt_kernel<<<(10 * 16384 + 255) / 256, 256, 0, stream>>>(W1, W2, wt);
    detect_kernel<<<1, 64, 0, stream>>>(ei, flag);
    hipMemsetAsync(deg, 0, (size_t)N * sizeof(int), stream);
    hist_kernel<<<(E + 255) / 256, 256, 0, stream>>>(ei, flag, deg, E, N);
    scan_kernel<<<1, 1024, 0, stream>>>(deg, off, N);
    hipMemsetAsync(cursor, 0, (size_t)N * sizeof(int), stream);
    fill_kernel<<<(E + 255) / 256, 256, 0, stream>>>(ei, flag, off, cursor, pack, E, N);

    // layers: l even: agg hin->OUT, gemm1 OUT->A, gemm2 A->OUT; l odd mirrored.
    const float* hin = x;
    int gemmBlocks = (N + 63) / 64;
    int aggBlocks  = (N + 3) / 4;
    float inv_n = 1.0f / (float)N;

    for (int l = 0; l < LAYERS; ++l) {
        float* Q = (l % 2 == 0) ? OUT : A;
        float* T = (l % 2 == 0) ? A : OUT;
        if (l == 0)
            agg_cvt_kernel<<<aggBlocks, 256, 0, stream>>>(x, ea, off, pack, eab, Q, colstats, N);
        else
            agg_kernel<<<aggBlocks, 256, 0, stream>>>(hin, eab, off, pack, Q, colstats, N);
        gemm_kernel<1><<<gemmBlocks, 256, 0, stream>>>(Q, wt + (size_t)l * 16384, b1 + l * D,
                                                       T, nullptr, colstats, N);
        bn_kernel<<<1, 128, 0, stream>>>(colstats, gamma + l * D, beta + l * D, ss, inv_n);
        gemm_kernel<2><<<gemmBlocks, 256, 0, stream>>>(T, wt + (size_t)(5 + l) * 16384, b2 + l * D,
                                                       Q, ss, nullptr, N);
        hin = Q;
    }
}

// Round 5
// 773.575 us; speedup vs baseline: 1.3759x; 1.2042x over previous
//
#include <hip/hip_runtime.h>
#include <hip/hip_bf16.h>
#include <stdint.h>

#define D 128
#define LAYERS 5
#define BN_EPS 1e-5f

typedef unsigned int uint32;
typedef __bf16 bf16x8 __attribute__((ext_vector_type(8)));
typedef float f32x4 __attribute__((ext_vector_type(4)));
typedef float f32x2 __attribute__((ext_vector_type(2)));

// fp32 -> bf16 bits, round-to-nearest-even
__device__ inline unsigned short f2bf(float f) {
    uint32 u = __float_as_uint(f);
    return (unsigned short)((u + 0x7fffu + ((u >> 16) & 1u)) >> 16);
}
__device__ inline float bflo(uint32 p) { return __uint_as_float(p << 16); }
__device__ inline float bfhi(uint32 p) { return __uint_as_float(p & 0xffff0000u); }
__device__ inline uint32 pack2(float a, float b) {
    return (uint32)f2bf(a) | ((uint32)f2bf(b) << 16);
}

// ---------------- edge_index layout detection ----------------

__global__ void detect_kernel(const int* __restrict__ ei, int* __restrict__ flag) {
    if (threadIdx.x == 0 && blockIdx.x == 0) {
        int allz = 1;
#pragma unroll
        for (int i = 0; i < 16; ++i) allz &= (ei[2 * i + 1] == 0);
        *flag = allz;  // 1 => int64 layout, 0 => int32 layout
    }
}

// ---------------- CSR build (dst -> incoming edges) ----------------

__global__ __launch_bounds__(256) void hist_kernel(const int* __restrict__ ei,
                                                   const int* __restrict__ flag,
                                                   int* __restrict__ deg, int E, int n) {
    int e = blockIdx.x * blockDim.x + threadIdx.x;
    if (e >= E) return;
    int is64 = *flag;
    int d = is64 ? ei[2 * ((size_t)E + e)] : ei[E + e];
    if ((unsigned)d < (unsigned)n) atomicAdd(&deg[d], 1);
}

__global__ __launch_bounds__(1024) void scan_kernel(const int* __restrict__ deg,
                                                    int* __restrict__ off, int n) {
    __shared__ int tsum[1024];
    int t = threadIdx.x;
    int CH = (n + 1023) >> 10;
    int lo = t * CH;
    int hi = lo + CH; if (hi > n) hi = n;
    int s = 0;
    for (int i = lo; i < hi; ++i) s += deg[i];
    tsum[t] = s;
    __syncthreads();
    for (int d = 1; d < 1024; d <<= 1) {
        int v = (t >= d) ? tsum[t - d] : 0;
        __syncthreads();
        tsum[t] += v;
        __syncthreads();
    }
    int run = tsum[t] - s;  // exclusive prefix
    for (int i = lo; i < hi; ++i) { off[i] = run; run += deg[i]; }
    if (t == 1023) off[n] = tsum[1023];
}

__global__ __launch_bounds__(256) void fill_kernel(const int* __restrict__ ei,
                                                   const int* __restrict__ flag,
                                                   const int* __restrict__ off,
                                                   int* __restrict__ cursor,
                                                   int* __restrict__ srcs,
                                                   int* __restrict__ eidx, int E, int n) {
    int e = blockIdx.x * blockDim.x + threadIdx.x;
    if (e >= E) return;
    int is64 = *flag;
    int d = is64 ? ei[2 * ((size_t)E + e)] : ei[E + e];
    int s = is64 ? ei[2 * (size_t)e] : ei[e];
    if ((unsigned)d >= (unsigned)n || (unsigned)s >= (unsigned)n) return;
    int p = atomicAdd(&cursor[d], 1);
    int pos = off[d] + p;
    srcs[pos] = s;
    eidx[pos] = e;
}

// ---------------- layer-0 aggregate (fp32 x, fp32 ea) fused with ea->bf16 CSR convert
// out(bf16)[i] = x[i] + sum_j relu(x[src]+ea);  eab[p] = bf16(ea[eidx[p]])
// one wave per node, 2 cols per lane; unroll x4 for latency hiding

__global__ __launch_bounds__(256) void agg_cvt_kernel(const float* __restrict__ x,
                                                      const float* __restrict__ ea,
                                                      const int* __restrict__ off,
                                                      const int* __restrict__ srcs,
                                                      const int* __restrict__ eidx,
                                                      uint32* __restrict__ eab,
                                                      uint32* __restrict__ out,
                                                      float* __restrict__ colstats, int n) {
    if (blockIdx.x == 0 && threadIdx.x < 256) colstats[threadIdx.x] = 0.f;
    int node = blockIdx.x * 4 + (threadIdx.x >> 6);
    if (node >= n) return;
    int lane = threadIdx.x & 63;
    int c = lane * 2;
    float2 acc = *(const float2*)(x + (size_t)node * D + c);
    int e = off[node], end = off[node + 1];
    for (; e + 4 <= end; e += 4) {
        int s0 = srcs[e], s1 = srcs[e + 1], s2 = srcs[e + 2], s3 = srcs[e + 3];
        int y0 = eidx[e], y1 = eidx[e + 1], y2 = eidx[e + 2], y3 = eidx[e + 3];
        f32x2 v0 = __builtin_nontemporal_load((const f32x2*)(ea + (size_t)y0 * D + c));
        f32x2 v1 = __builtin_nontemporal_load((const f32x2*)(ea + (size_t)y1 * D + c));
        f32x2 v2 = __builtin_nontemporal_load((const f32x2*)(ea + (size_t)y2 * D + c));
        f32x2 v3 = __builtin_nontemporal_load((const f32x2*)(ea + (size_t)y3 * D + c));
        float2 h0 = *(const float2*)(x + (size_t)s0 * D + c);
        float2 h1 = *(const float2*)(x + (size_t)s1 * D + c);
        float2 h2 = *(const float2*)(x + (size_t)s2 * D + c);
        float2 h3 = *(const float2*)(x + (size_t)s3 * D + c);
        acc.x += fmaxf(h0.x + v0.x, 0.f) + fmaxf(h1.x + v1.x, 0.f)
               + fmaxf(h2.x + v2.x, 0.f) + fmaxf(h3.x + v3.x, 0.f);
        acc.y += fmaxf(h0.y + v0.y, 0.f) + fmaxf(h1.y + v1.y, 0.f)
               + fmaxf(h2.y + v2.y, 0.f) + fmaxf(h3.y + v3.y, 0.f);
        __builtin_nontemporal_store(pack2(v0.x, v0.y), eab + (size_t)e * 64 + lane);
        __builtin_nontemporal_store(pack2(v1.x, v1.y), eab + (size_t)(e + 1) * 64 + lane);
        __builtin_nontemporal_store(pack2(v2.x, v2.y), eab + (size_t)(e + 2) * 64 + lane);
        __builtin_nontemporal_store(pack2(v3.x, v3.y), eab + (size_t)(e + 3) * 64 + lane);
    }
    for (; e < end; ++e) {
        int s0 = srcs[e], y0 = eidx[e];
        float2 v0 = *(const float2*)(ea + (size_t)y0 * D + c);
        float2 h0 = *(const float2*)(x + (size_t)s0 * D + c);
        acc.x += fmaxf(h0.x + v0.x, 0.f);
        acc.y += fmaxf(h0.y + v0.y, 0.f);
        eab[(size_t)e * 64 + lane] = pack2(v0.x, v0.y);
    }
    out[(size_t)node * 64 + lane] = pack2(acc.x, acc.y);
}

// ---------------- aggregate (layers 1+): bf16 h, bf16 ea, CSR-sequential, unroll x4

__global__ __launch_bounds__(256) void agg_kernel(const uint32* __restrict__ h,
                                                  const uint32* __restrict__ eab,
                                                  const int* __restrict__ off,
                                                  const int* __restrict__ srcs,
                                                  uint32* __restrict__ out,
                                                  float* __restrict__ colstats, int n) {
    if (blockIdx.x == 0 && threadIdx.x < 256) colstats[threadIdx.x] = 0.f;
    int node = blockIdx.x * 4 + (threadIdx.x >> 6);
    if (node >= n) return;
    int lane = threadIdx.x & 63;
    uint32 hn = h[(size_t)node * 64 + lane];
    float2 acc = make_float2(bflo(hn), bfhi(hn));
    int e = off[node], end = off[node + 1];
    for (; e + 4 <= end; e += 4) {
        int s0 = srcs[e], s1 = srcs[e + 1], s2 = srcs[e + 2], s3 = srcs[e + 3];
        uint32 a0 = __builtin_nontemporal_load(eab + (size_t)e * 64 + lane);
        uint32 a1 = __builtin_nontemporal_load(eab + (size_t)(e + 1) * 64 + lane);
        uint32 a2 = __builtin_nontemporal_load(eab + (size_t)(e + 2) * 64 + lane);
        uint32 a3 = __builtin_nontemporal_load(eab + (size_t)(e + 3) * 64 + lane);
        uint32 h0 = h[(size_t)s0 * 64 + lane];
        uint32 h1 = h[(size_t)s1 * 64 + lane];
        uint32 h2 = h[(size_t)s2 * 64 + lane];
        uint32 h3 = h[(size_t)s3 * 64 + lane];
        acc.x += fmaxf(bflo(h0) + bflo(a0), 0.f) + fmaxf(bflo(h1) + bflo(a1), 0.f)
               + fmaxf(bflo(h2) + bflo(a2), 0.f) + fmaxf(bflo(h3) + bflo(a3), 0.f);
        acc.y += fmaxf(bfhi(h0) + bfhi(a0), 0.f) + fmaxf(bfhi(h1) + bfhi(a1), 0.f)
               + fmaxf(bfhi(h2) + bfhi(a2), 0.f) + fmaxf(bfhi(h3) + bfhi(a3), 0.f);
    }
    for (; e < end; ++e) {
        int s0 = srcs[e];
        uint32 a0 = eab[(size_t)e * 64 + lane];
        uint32 h0 = h[(size_t)s0 * 64 + lane];
        acc.x += fmaxf(bflo(h0) + bflo(a0), 0.f);
        acc.y += fmaxf(bfhi(h0) + bfhi(a0), 0.f);
    }
    out[(size_t)node * 64 + lane] = pack2(acc.x, acc.y);
}

// ---------------- W -> Wt bf16 transpose-convert: wt[l][n][k] = bf16(W[l][k][n]) ----

__global__ __launch_bounds__(256) void wt_kernel(const float* __restrict__ W1,
                                                 const float* __restrict__ W2,
                                                 unsigned short* __restrict__ wt) {
    int id = blockIdx.x * 256 + threadIdx.x;
    if (id >= 10 * 16384) return;
    int l = id >> 14;
    int rem = id & 16383;
    int nn = rem >> 7, kk = rem & 127;
    const float* base = (l < 5) ? (W1 + (size_t)l * 16384) : (W2 + (size_t)(l - 5) * 16384);
    wt[(size_t)l * 16384 + nn * 128 + kk] = f2bf(base[kk * 128 + nn]);
}

// ---------------- MFMA GEMM: out[N,128] = f(A)[N,128] @ W[128,128] + bias ----------
// A is bf16 [N][128]. MODE 1: f=id, accumulate col sum/sumsq of fp32 output into
// colstats. MODE 2: f(x)=relu(sc[k]*x+sh[k]) with sc/sh computed in-block from
// colstats/gamma/beta (BN folded). F32OUT: write fp32 (final layer) else bf16.
// 256 thr = 4 waves; wave w -> rows blockIdx*64 + w*16; loop 8 col-tiles of 16.
// mfma_f32_16x16x32_bf16: A row=l&15, k=8*(l>>4)+j; B col=l&15; D row=(l>>4)*4+r.

template <int MODE, bool F32OUT>
__global__ __launch_bounds__(256) void gemm_kernel(const uint4* __restrict__ A,
                                                   const uint4* __restrict__ Wt4,
                                                   const float* __restrict__ bias,
                                                   void* __restrict__ outp,
                                                   float* __restrict__ colstats,
                                                   const float* __restrict__ gamma,
                                                   const float* __restrict__ beta,
                                                   float inv_n, int n) {
    __shared__ float red[256];
    const int t = threadIdx.x;
    const int wv = t >> 6, l = t & 63;
    const int lrow = l & 15, lk = l >> 4;
    const int r0 = blockIdx.x * 64 + wv * 16;

    if (MODE == 1) {
        red[t] = 0.f;
    } else {
        if (t < 128) {
            float mu = colstats[t] * inv_n;
            float var = colstats[128 + t] * inv_n - mu * mu;
            float inv = rsqrtf(var + BN_EPS);
            float sc = gamma[t] * inv;
            red[t] = sc;
            red[128 + t] = beta[t] - mu * sc;
        }
    }
    __syncthreads();

    // A fragments for the wave's 16 rows, all K=128 (4 chunks of 32)
    bf16x8 af[4];
    const int arow = r0 + lrow;
    const bool rowok = arow < n;
#pragma unroll
    for (int c = 0; c < 4; ++c) {
        union { uint4 u; bf16x8 v; uint32 w[4]; } bu;
        bu.u = make_uint4(0u, 0u, 0u, 0u);
        if (rowok) bu.u = A[(size_t)arow * 16 + c * 4 + lk];
        if (MODE == 2) {
            const int kb = c * 32 + lk * 8;
            float xv[8];
#pragma unroll
            for (int i = 0; i < 4; ++i) {
                xv[2 * i]     = bflo(bu.w[i]);
                xv[2 * i + 1] = bfhi(bu.w[i]);
            }
#pragma unroll
            for (int j = 0; j < 8; ++j)
                xv[j] = fmaxf(fmaf(red[kb + j], xv[j], red[128 + kb + j]), 0.f);
#pragma unroll
            for (int i = 0; i < 4; ++i)
                bu.w[i] = pack2(xv[2 * i], xv[2 * i + 1]);
        }
        af[c] = bu.v;
    }

    float* outF = (float*)outp;
    unsigned short* outB = (unsigned short*)outp;
    float s[8], s2[8];

#pragma unroll
    for (int n0 = 0; n0 < 8; ++n0) {
        const int wcol = n0 * 16 + lrow;
        f32x4 acc = {0.f, 0.f, 0.f, 0.f};
#pragma unroll
        for (int c = 0; c < 4; ++c) {
            union { uint4 u; bf16x8 v; } bu;
            bu.u = Wt4[wcol * 16 + c * 4 + lk];
            acc = __builtin_amdgcn_mfma_f32_16x16x32_bf16(af[c], bu.v, acc, 0, 0, 0);
        }
        const float bcol = bias[wcol];
        float ls = 0.f, ls2 = 0.f;
#pragma unroll
        for (int r = 0; r < 4; ++r) {
            int row = r0 + lk * 4 + r;
            float v = acc[r] + bcol;
            if (row < n) {
                if (F32OUT) outF[(size_t)row * D + wcol] = v;
                else        outB[(size_t)row * D + wcol] = f2bf(v);
                if (MODE == 1) { ls += v; ls2 += v * v; }
            }
        }
        s[n0] = ls; s2[n0] = ls2;
    }

    if (MODE == 1) {
#pragma unroll
        for (int n0 = 0; n0 < 8; ++n0) {
            const int wcol = n0 * 16 + lrow;
            float ls = s[n0], ls2 = s2[n0];
            ls  += __shfl_xor(ls, 16);  ls  += __shfl_xor(ls, 32);
            ls2 += __shfl_xor(ls2, 16); ls2 += __shfl_xor(ls2, 32);
            if (lk == 0) {
                atomicAdd(&red[wcol], ls);
                atomicAdd(&red[D + wcol], ls2);
            }
        }
        __syncthreads();
        if (t < 128) {
            atomicAdd(&colstats[t], red[t]);
            atomicAdd(&colstats[D + t], red[D + t]);
        }
    }
}

// ---------------- launch ----------------

extern "C" void kernel_launch(void* const* d_in, const int* in_sizes, int n_in,
                              void* d_out, int out_size, void* d_ws, size_t ws_size,
                              hipStream_t stream) {
    const float* x      = (const float*)d_in[0];
    const int*   ei     = (const int*)d_in[1];
    const float* ea     = (const float*)d_in[2];
    const float* W1     = (const float*)d_in[3];
    const float* b1     = (const float*)d_in[4];
    const float* gamma  = (const float*)d_in[5];
    const float* beta   = (const float*)d_in[6];
    const float* W2     = (const float*)d_in[7];
    const float* b2     = (const float*)d_in[8];
    const int N = in_sizes[0] / D;
    const int E = in_sizes[1] / 2;

    char* w = (char*)d_ws;
    auto alloc = [&](size_t bytes) {
        char* p = w;
        w += (bytes + 255) & ~(size_t)255;
        return p;
    };
    int*    off      = (int*)alloc((size_t)(N + 1) * sizeof(int));
    int*    deg      = (int*)alloc((size_t)N * sizeof(int));
    int*    cursor   = (int*)alloc((size_t)N * sizeof(int));
    int*    flag     = (int*)alloc(256);
    float*  colstats = (float*)alloc(256 * sizeof(float));
    unsigned short* wt = (unsigned short*)alloc(10 * 16384 * sizeof(unsigned short));
    int*    srcs     = (int*)alloc((size_t)E * sizeof(int));
    int*    eidx     = (int*)alloc((size_t)E * sizeof(int));
    uint32* eab      = (uint32*)alloc((size_t)E * 64 * sizeof(uint32));
    uint32* G        = (uint32*)alloc((size_t)N * 64 * sizeof(uint32));  // agg out (bf16)
    uint32* T        = (uint32*)alloc((size_t)N * 64 * sizeof(uint32));  // gemm1 out (bf16)
    uint32* H        = (uint32*)alloc((size_t)N * 64 * sizeof(uint32));  // gemm2 out (bf16)

    // W transpose+bf16 convert, CSR build
    wt_kernel<<<(10 * 16384 + 255) / 256, 256, 0, stream>>>(W1, W2, wt);
    detect_kernel<<<1, 64, 0, stream>>>(ei, flag);
    hipMemsetAsync(deg, 0, (size_t)N * sizeof(int), stream);
    hist_kernel<<<(E + 255) / 256, 256, 0, stream>>>(ei, flag, deg, E, N);
    scan_kernel<<<1, 1024, 0, stream>>>(deg, off, N);
    hipMemsetAsync(cursor, 0, (size_t)N * sizeof(int), stream);
    fill_kernel<<<(E + 255) / 256, 256, 0, stream>>>(ei, flag, off, cursor, srcs, eidx, E, N);

    int gemmBlocks = (N + 63) / 64;
    int aggBlocks  = (N + 3) / 4;
    float inv_n = 1.0f / (float)N;

    for (int l = 0; l < LAYERS; ++l) {
        if (l == 0)
            agg_cvt_kernel<<<aggBlocks, 256, 0, stream>>>(x, ea, off, srcs, eidx, eab, G,
                                                          colstats, N);
        else
            agg_kernel<<<aggBlocks, 256, 0, stream>>>(H, eab, off, srcs, G, colstats, N);
        gemm_kernel<1, false><<<gemmBlocks, 256, 0, stream>>>(
            (const uint4*)G, (const uint4*)(wt + (size_t)l * 16384), b1 + l * D,
            T, colstats, nullptr, nullptr, inv_n, N);
        if (l < LAYERS - 1)
            gemm_kernel<2, false><<<gemmBlocks, 256, 0, stream>>>(
                (const uint4*)T, (const uint4*)(wt + (size_t)(5 + l) * 16384), b2 + l * D,
                H, colstats, gamma + l * D, beta + l * D, inv_n, N);
        else
            gemm_kernel<2, true><<<gemmBlocks, 256, 0, stream>>>(
                (const uint4*)T, (const uint4*)(wt + (size_t)(5 + l) * 16384), b2 + l * D,
                d_out, colstats, gamma + l * D, beta + l * D, inv_n, N);
    }
}